// Round 11
// baseline (305.158 us; speedup 1.0000x reference)
//
#include <hip/hip_runtime.h>
#include <hip/hip_bf16.h>
#include <cstdint>
#include <math.h>

#define T 2048
#define NE 1024
#define NB 4

typedef __attribute__((ext_vector_type(8))) short short8;
typedef __attribute__((ext_vector_type(4))) short shortx4;
typedef __attribute__((ext_vector_type(4))) float floatx4;

__device__ __forceinline__ unsigned short f2bf(float f) {
    unsigned u = __float_as_uint(f);
    u += 0x7FFF + ((u >> 16) & 1);   // RNE
    return (unsigned short)(u >> 16);
}

__device__ __forceinline__ shortx4 cvt4(floatx4 f) {
    __hip_bfloat162 a = __float22bfloat162_rn(float2{f[0], f[1]});
    __hip_bfloat162 b = __float22bfloat162_rn(float2{f[2], f[3]});
    union { shortx4 s; unsigned u[2]; } r;
    r.u[0] = *(unsigned*)&a; r.u[1] = *(unsigned*)&b;
    return r.s;
}

__device__ __forceinline__ void gl2lds(const void* g, void* l) {
    __builtin_amdgcn_global_load_lds(
        (const __attribute__((address_space(1))) void*)g,
        (__attribute__((address_space(3))) void*)l, 16, 0, 0);
}

// C[m,n] = scale * sum_k A[m,k]*B[n,k] (+ bias) — bf16 in, f32/bf16 out.
// Tile (NWROW*64) x 128, BK=64, NWROW*128 threads (2*NWROW waves, 64x64/wave).
// LDS swizzle: logical chunk c of row r at physical chunk c^(r&7).
// MODE: 0 plain | 1 xcd tm-band (ntnShift) | 2 tri 17/xcd |
//       4 PV complementary-pair: 64 blk/z (xcd=bid&7, tn=bid>>3); two passes,
//       tm = 15-xcd then xcd -> K sum 17*128 for EVERY block (34 iters).
// EPI: 0 plain | 1 exp+rowsum-PARTIALS: causal mask, writes exp(S*scale);
//      per-tile row sums -> part[(bz*16+tn)*T + m]. Cross-wave (wn halves)
//      combine via LDS reuse of As + one syncthreads — no atomics, no memset.
//      (r9 BUG fixed: both wn waves previously stored half-sums to rs[m].)
//      | 2 rowdiv: row m divided by sum_{t<=tm} part — D^-1 commutes with PV.
template<int NWROW, int BIAS_MODE, bool OUT_F32, bool CKLIM, bool DUAL, int MODE, int EPI>
__global__ __launch_bounds__(NWROW * 128, 4) void gemm_bf16(
    const unsigned short* __restrict__ A0, const unsigned short* __restrict__ A1,
    const unsigned short* __restrict__ B0, const unsigned short* __restrict__ B1,
    const float* __restrict__ bias0, const float* __restrict__ bias1,
    void* __restrict__ C0, void* __restrict__ C1,
    int K, int lda, int ldb, int ldc,
    size_t sA, size_t sB, size_t sC, float scale, int ntnShift)
{
    constexpr int NTHR = NWROW * 128;
    constexpr int PASSES = (MODE == 4) ? 2 : 1;
    int tm = 0, tn;
    const int bz = blockIdx.z;
    if (MODE == 2) {           // xcd-grouped lower-triangular decode
        const int i = blockIdx.x;
        int lin = (i & 7) * 17 + (i >> 3);
        tm = (int)((sqrtf(8.f * (float)lin + 1.f) - 1.f) * 0.5f);
        while ((tm + 1) * (tm + 2) / 2 <= lin) ++tm;
        while (tm * (tm + 1) / 2 > lin) --tm;
        tn = lin - tm * (tm + 1) / 2;
    } else if (MODE == 1) {    // xcd gets contiguous tm band x all tn
        const int bid = blockIdx.x;
        const int lin = (bid & 7) * (gridDim.x >> 3) + (bid >> 3);
        tm = lin >> ntnShift; tn = lin & ((1 << ntnShift) - 1);
    } else if (MODE == 4) {    // tm set per pass inside the loop
        tn = blockIdx.x >> 3;
    } else {
        tn = blockIdx.x; tm = blockIdx.y;
    }

    __shared__ __align__(16) char As[NWROW * 64 * 128];
    __shared__ __align__(16) char Bs[128 * 128];

    const int tid = threadIdx.x, lane = tid & 63, wave = tid >> 6;
    const int wm = wave % NWROW, wn = wave / NWROW;
    const int quad = lane >> 4, l15 = lane & 15;
    const int p = l15 & 7;                 // swizzle parity of fragment rows
    const int r8 = lane >> 3, c8 = lane & 7;

    const char* Ab = (const char*)((DUAL && bz) ? A1 : A0) + (size_t)bz * sA * 2;
    const char* Bb = (const char*)((DUAL && bz) ? B1 : B0) + (size_t)bz * sB * 2;
    const float* bias = (DUAL && bz) ? bias1 : bias0;

    const size_t ldab = (size_t)lda * 2, ldbb = (size_t)ldb * 2;
    const char* gB = Bb + (size_t)(tn * 128 + wave * 8 + r8) * ldbb + (size_t)((c8 ^ r8) * 16);
    char* lA = As + wave * 1024;
    char* lB = Bs + wave * 1024;
    constexpr int BCALLS = 8 / NWROW;
    char* Cb = (char*)((DUAL && bz) ? C1 : C0) + (size_t)bz * sC * (OUT_F32 ? 4 : 2);

    for (int pass = 0; pass < PASSES; ++pass) {
        if (MODE == 4) tm = pass == 0 ? 15 - (blockIdx.x & 7) : (blockIdx.x & 7);

        int Keff = K;
        if (CKLIM) { int kl = (tm + 1) * 128; Keff = kl < K ? kl : K; }

        const char* gA = Ab + (size_t)(tm * (NWROW * 64) + wave * 8 + r8) * ldab + (size_t)((c8 ^ r8) * 16);

        floatx4 acc[4][4] = {};

        for (int k0 = 0; k0 < Keff; k0 += 64) {
            const size_t kb = (size_t)k0 * 2;
            #pragma unroll
            for (int c = 0; c < 4; ++c)
                gl2lds(gA + (size_t)(c * NWROW * 16) * ldab + kb, lA + c * NTHR * 16);
            #pragma unroll
            for (int c = 0; c < BCALLS; ++c)
                gl2lds(gB + (size_t)(c * NWROW * 16) * ldbb + kb, lB + c * NTHR * 16);
            __syncthreads();

            #pragma unroll
            for (int kk = 0; kk < 2; kk++) {
                short8 af[4], bfr[4];
                #pragma unroll
                for (int i = 0; i < 4; i++)
                    af[i] = *(const short8*)(As + (wm * 64 + i * 16 + l15) * 128 + (((kk * 4 + quad) ^ p) << 4));
                #pragma unroll
                for (int j = 0; j < 4; j++)
                    bfr[j] = *(const short8*)(Bs + (wn * 64 + j * 16 + l15) * 128 + (((kk * 4 + quad) ^ p) << 4));
                #pragma unroll
                for (int i = 0; i < 4; i++)
                    #pragma unroll
                    for (int j = 0; j < 4; j++)
                        acc[i][j] = __builtin_amdgcn_mfma_f32_16x16x32_bf16(af[i], bfr[j], acc[i][j], 0, 0, 0);
            }
            __syncthreads();
        }

        // Epilogue: C/D layout col = lane&15, row = quad*4 + reg  [verified]
        if constexpr (EPI == 1) {
            // exp + causal mask; per-wave half-row sums -> LDS -> combined store
            float* rs = (float*)C1 + ((size_t)bz * 16 + tn) * T;
            float* lsum = (float*)As;   // reuse A LDS: [wn][128 tile rows]
            #pragma unroll
            for (int i = 0; i < 4; i++) {
                #pragma unroll
                for (int r = 0; r < 4; r++) {
                    const int mrow = wm * 64 + i * 16 + quad * 4 + r;
                    const int m = tm * (NWROW * 64) + mrow;
                    float rsum = 0.f;
                    #pragma unroll
                    for (int j = 0; j < 4; j++) {
                        const int n = tn * 128 + wn * 64 + j * 16 + l15;
                        float e = 0.f;
                        if (n <= m) e = __expf(acc[i][j][r] * scale);
                        rsum += e;
                        ((unsigned short*)Cb)[(size_t)m * ldc + n] = f2bf(e);
                    }
                    rsum += __shfl_xor(rsum, 1);
                    rsum += __shfl_xor(rsum, 2);
                    rsum += __shfl_xor(rsum, 4);
                    rsum += __shfl_xor(rsum, 8);
                    if (l15 == 0) lsum[wn * 128 + mrow] = rsum;
                }
            }
            __syncthreads();
            if (tid < 128)
                rs[tm * (NWROW * 64) + tid] = lsum[tid] + lsum[128 + tid];
        } else {
            float inv[4][4];
            if constexpr (EPI == 2) {
                const float* rsp = bias0 + (size_t)bz * 16 * T;
                #pragma unroll
                for (int i = 0; i < 4; i++)
                    #pragma unroll
                    for (int r = 0; r < 4; r++) {
                        const int m = tm * (NWROW * 64) + wm * 64 + i * 16 + quad * 4 + r;
                        float s = 0.f;
                        for (int t = 0; t <= tm; ++t)
                            s += rsp[(size_t)t * T + m];
                        inv[i][r] = 1.0f / s;
                    }
            }
            #pragma unroll
            for (int i = 0; i < 4; i++) {
                #pragma unroll
                for (int j = 0; j < 4; j++) {
                    const int n = tn * 128 + wn * 64 + j * 16 + l15;
                    #pragma unroll
                    for (int r = 0; r < 4; r++) {
                        const int m = tm * (NWROW * 64) + wm * 64 + i * 16 + quad * 4 + r;
                        float val = acc[i][j][r] * scale;
                        if (BIAS_MODE == 1) val += bias[n];
                        if (BIAS_MODE == 2) val += bias[m];
                        if (EPI == 2) val *= inv[i][r];
                        if (OUT_F32) ((float*)Cb)[(size_t)m * ldc + n] = val;
                        else         ((unsigned short*)Cb)[(size_t)m * ldc + n] = f2bf(val);
                    }
                }
            }
        }
    }
}

// Fused steps 1+2: one launch, block-range decode. Blocks 0..1023 = qp/kp
// projections; blocks 1024..1535 = vpT. bid%8 (XCD) preserved for both.
__global__ __launch_bounds__(256, 4) void fused12(
    const unsigned short* __restrict__ qb, const unsigned short* __restrict__ kb,
    const unsigned short* __restrict__ vb,
    const unsigned short* __restrict__ wqb, const unsigned short* __restrict__ wkb,
    const unsigned short* __restrict__ wvb,
    const float* __restrict__ wq_b, const float* __restrict__ wk_b,
    const float* __restrict__ wv_b,
    unsigned short* __restrict__ qp, unsigned short* __restrict__ kp,
    unsigned short* __restrict__ vpT)
{
    const int bid = blockIdx.x;
    const unsigned short *A, *B; const float* bias; unsigned short* C;
    int tm, tn, ldc, biasN;   // biasN: 1 -> bias[n], 0 -> bias[m]
    if (bid < 1024) {
        const int z = bid >> 9, l0 = bid & 511;
        const int lin = (l0 & 7) * 64 + (l0 >> 3);
        tm = lin >> 3; tn = lin & 7;
        A = z ? kb : qb; B = z ? wkb : wqb; bias = z ? wk_b : wq_b; C = z ? kp : qp;
        ldc = NE; biasN = 1;
    } else {
        const int t = bid - 1024, z = t >> 7, l0 = t & 127;
        const int lin = (l0 & 7) * 16 + (l0 >> 3);
        tm = lin >> 4; tn = lin & 15;
        A = wvb; B = vb + (size_t)z * T * NE; bias = wv_b; C = vpT + (size_t)z * NE * T;
        ldc = T; biasN = 0;
    }

    __shared__ __align__(16) char As[128 * 128];
    __shared__ __align__(16) char Bs[128 * 128];

    const int tid = threadIdx.x, lane = tid & 63, wave = tid >> 6;
    const int wm = wave & 1, wn = wave >> 1;
    const int quad = lane >> 4, l15 = lane & 15;
    const int p = l15 & 7;
    const int r8 = lane >> 3, c8 = lane & 7;

    const size_t ldab = (size_t)NE * 2;
    const char* gA = (const char*)A + (size_t)(tm * 128 + wave * 8 + r8) * ldab + (size_t)((c8 ^ r8) * 16);
    const char* gB = (const char*)B + (size_t)(tn * 128 + wave * 8 + r8) * ldab + (size_t)((c8 ^ r8) * 16);
    char* lA = As + wave * 1024;
    char* lB = Bs + wave * 1024;

    floatx4 acc[4][4] = {};

    for (int k0 = 0; k0 < NE; k0 += 64) {
        const size_t kb2 = (size_t)k0 * 2;
        #pragma unroll
        for (int c = 0; c < 4; ++c)
            gl2lds(gA + (size_t)(c * 32) * ldab + kb2, lA + c * 4096);
        #pragma unroll
        for (int c = 0; c < 4; ++c)
            gl2lds(gB + (size_t)(c * 32) * ldab + kb2, lB + c * 4096);
        __syncthreads();

        #pragma unroll
        for (int kk = 0; kk < 2; kk++) {
            short8 af[4], bfr[4];
            #pragma unroll
            for (int i = 0; i < 4; i++)
                af[i] = *(const short8*)(As + (wm * 64 + i * 16 + l15) * 128 + (((kk * 4 + quad) ^ p) << 4));
            #pragma unroll
            for (int j = 0; j < 4; j++)
                bfr[j] = *(const short8*)(Bs + (wn * 64 + j * 16 + l15) * 128 + (((kk * 4 + quad) ^ p) << 4));
            #pragma unroll
            for (int i = 0; i < 4; i++)
                #pragma unroll
                for (int j = 0; j < 4; j++)
                    acc[i][j] = __builtin_amdgcn_mfma_f32_16x16x32_bf16(af[i], bfr[j], acc[i][j], 0, 0, 0);
        }
        __syncthreads();
    }

    #pragma unroll
    for (int i = 0; i < 4; i++) {
        #pragma unroll
        for (int j = 0; j < 4; j++) {
            const int n = tn * 128 + wn * 64 + j * 16 + l15;
            #pragma unroll
            for (int r = 0; r < 4; r++) {
                const int m = tm * 128 + wm * 64 + i * 16 + quad * 4 + r;
                float val = acc[i][j][r] + (biasN ? bias[n] : bias[m]);
                C[(size_t)m * ldc + n] = f2bf(val);
            }
        }
    }
}

// Bulk f32->bf16: q,k,v then wq,wk,wv. One float4 per thread. Nontemporal
// load+store: read-once/write-once data; nt keeps the 54 MB write stream
// from write-allocating into (and evicting) the 32 MB aggregate L2.
__global__ __launch_bounds__(256) void cvt_all(
    const float* __restrict__ q, const float* __restrict__ k, const float* __restrict__ v,
    const float* __restrict__ wq, const float* __restrict__ wk, const float* __restrict__ wv,
    unsigned short* __restrict__ qb, unsigned short* __restrict__ kb, unsigned short* __restrict__ vb,
    unsigned short* __restrict__ wqb, unsigned short* __restrict__ wkb, unsigned short* __restrict__ wvb)
{
    const int IN4 = NB * T * NE / 4;   // 2^21
    const int W4  = NE * NE / 4;       // 2^18
    int i = blockIdx.x * 256 + threadIdx.x;
    const float* s; unsigned short* d; int j;
    if (i < 3 * IN4) {
        int sel = i >> 21; j = i & (IN4 - 1);
        s = sel == 0 ? q : sel == 1 ? k : v;
        d = sel == 0 ? qb : sel == 1 ? kb : vb;
    } else {
        int t2 = i - 3 * IN4; int sel = t2 >> 18; j = t2 & (W4 - 1);
        s = sel == 0 ? wq : sel == 1 ? wk : wv;
        d = sel == 0 ? wqb : sel == 1 ? wkb : wvb;
    }
    floatx4 f = __builtin_nontemporal_load((const floatx4*)s + j);
    __builtin_nontemporal_store(cvt4(f), (shortx4*)d + j);
}

extern "C" void kernel_launch(void* const* d_in, const int* in_sizes, int n_in,
                              void* d_out, int out_size, void* d_ws, size_t ws_size,
                              hipStream_t stream)
{
    const float* q    = (const float*)d_in[0];
    const float* k    = (const float*)d_in[1];
    const float* v    = (const float*)d_in[2];
    const float* wq_w = (const float*)d_in[3];
    const float* wq_b = (const float*)d_in[4];
    const float* wk_w = (const float*)d_in[5];
    const float* wk_b = (const float*)d_in[6];
    const float* wv_w = (const float*)d_in[7];
    const float* wv_b = (const float*)d_in[8];

    const size_t INEL = (size_t)NB * T * NE;

    unsigned short* qp = (unsigned short*)d_out;        // qp/kp scratch in d_out
    unsigned short* kp = qp + INEL;

    unsigned short* vpT = (unsigned short*)d_ws;        // [0,16) MB
    unsigned short* S   = vpT + (size_t)NB * NE * T;    // [16, 49.6) MB
    unsigned short* qb  = S;                            // staging region
    unsigned short* kb  = qb + INEL;                    // overlaps S in space,
    unsigned short* vb  = kb + INEL;                    // disjoint in time
    unsigned short* wqb = vb + INEL;
    unsigned short* wkb = wqb + (size_t)NE * NE;
    unsigned short* wvb = wkb + (size_t)NE * NE;
    // rowsum partials: 16 x T x NB f32 = 512 KB at +52 MB — after S end
    // (49.6 MB), inside vb zone (dead after fused12). Written by step3
    // (per-tile, no atomics/memset), summed by step5's epilogue.
    float* part = (float*)((char*)d_ws + 52ull * 1024 * 1024);

    dim3 blk(256);

    // 0) all f32 -> bf16
    const int NCVT = (3 * (int)(INEL / 4) + 3 * NE * NE / 4 + 255) / 256;
    cvt_all<<<dim3(NCVT), blk, 0, stream>>>(q, k, v, wq_w, wk_w, wv_w, qb, kb, vb, wqb, wkb, wvb);

    // 1+2) qp/kp projections AND vpT in ONE launch (1536 blocks, range-decoded)
    fused12<<<dim3(1536), blk, 0, stream>>>(
        qb, kb, vb, wqb, wkb, wvb, wq_b, wk_b, wv_b, qp, kp, vpT);

    // 3) S[b] = exp(qp_b @ kp_b^T / 32) causal + rowsum partials —
    //    136 tri tiles (128x128), xcd-grouped. No memset needed.
    gemm_bf16<2, 0, false, false, false, 2, 1><<<dim3(136, 1, NB), blk, 0, stream>>>(
        qp, nullptr, kp, nullptr, nullptr, nullptr, S, part,
        NE, NE, NE, T, (size_t)T * NE, (size_t)T * NE, (size_t)T * T, 0.03125f, 0);

    // 5) O[b] = D^-1 (P_b @ vpT_b^T) — MODE 4 complementary pairs: 64 blk/z,
    //    every block 34 K-iters; epilogue sums <=16 rowsum partials per row.
    gemm_bf16<2, 0, true, true, false, 4, 2><<<dim3(64, 1, NB), blk, 0, stream>>>(
        S, nullptr, vpT, nullptr, part, nullptr, d_out, nullptr,
        T, T, T, NE, (size_t)T * T, (size_t)NE * T, (size_t)T * NE, 1.0f, 0);
}

// Round 12
// 284.064 us; speedup vs baseline: 1.0743x; 1.0743x over previous
//
#include <hip/hip_runtime.h>
#include <hip/hip_bf16.h>
#include <cstdint>
#include <math.h>

#define T 2048
#define NE 1024
#define NB 4

typedef __attribute__((ext_vector_type(8))) short short8;
typedef __attribute__((ext_vector_type(4))) short shortx4;
typedef __attribute__((ext_vector_type(4))) float floatx4;

__device__ __forceinline__ unsigned short f2bf(float f) {
    unsigned u = __float_as_uint(f);
    u += 0x7FFF + ((u >> 16) & 1);   // RNE
    return (unsigned short)(u >> 16);
}

__device__ __forceinline__ shortx4 cvt4(floatx4 f) {
    __hip_bfloat162 a = __float22bfloat162_rn(float2{f[0], f[1]});
    __hip_bfloat162 b = __float22bfloat162_rn(float2{f[2], f[3]});
    union { shortx4 s; unsigned u[2]; } r;
    r.u[0] = *(unsigned*)&a; r.u[1] = *(unsigned*)&b;
    return r.s;
}

__device__ __forceinline__ void gl2lds(const void* g, void* l) {
    __builtin_amdgcn_global_load_lds(
        (const __attribute__((address_space(1))) void*)g,
        (__attribute__((address_space(3))) void*)l, 16, 0, 0);
}

// C[m,n] = scale * sum_k A[m,k]*B[n,k] (+ bias) — bf16 in, f32/bf16 out.
// Tile (NWROW*64) x 128, BK=64, NWROW*128 threads (2*NWROW waves, 64x64/wave).
// LDS swizzle: logical chunk c of row r at physical chunk c^(r&7).
// MODE: 0 plain | 1 xcd tm-band (ntnShift) | 2 tri 17/xcd |
//       4 PV complementary-pair: 64 blk/z (xcd=bid&7, tn=bid>>3); two passes,
//       tm = 15-xcd then xcd -> K sum 17*128 for EVERY block (34 iters).
// EPI: 0 plain | 1 exp+rowsum (causal mask, writes exp(S*scale), atomicAdds
//      f32 row sums into (float*)C1 + bz*T) | 2 rowdiv (divides output row m
//      by rowsum[m] from bias0 + bz*T — D^-1 commutes with PV).
// [r11 lessons: nt stores on cvt outputs cost fused12 +10us (cache-cold
//  refetch); partial-rowsum scheme cost more than the memset it saved.]
template<int NWROW, int BIAS_MODE, bool OUT_F32, bool CKLIM, bool DUAL, int MODE, int EPI>
__global__ __launch_bounds__(NWROW * 128, 4) void gemm_bf16(
    const unsigned short* __restrict__ A0, const unsigned short* __restrict__ A1,
    const unsigned short* __restrict__ B0, const unsigned short* __restrict__ B1,
    const float* __restrict__ bias0, const float* __restrict__ bias1,
    void* __restrict__ C0, void* __restrict__ C1,
    int K, int lda, int ldb, int ldc,
    size_t sA, size_t sB, size_t sC, float scale, int ntnShift)
{
    constexpr int NTHR = NWROW * 128;
    constexpr int PASSES = (MODE == 4) ? 2 : 1;
    int tm = 0, tn;
    const int bz = blockIdx.z;
    if (MODE == 2) {           // xcd-grouped lower-triangular decode
        const int i = blockIdx.x;
        int lin = (i & 7) * 17 + (i >> 3);
        tm = (int)((sqrtf(8.f * (float)lin + 1.f) - 1.f) * 0.5f);
        while ((tm + 1) * (tm + 2) / 2 <= lin) ++tm;
        while (tm * (tm + 1) / 2 > lin) --tm;
        tn = lin - tm * (tm + 1) / 2;
    } else if (MODE == 1) {    // xcd gets contiguous tm band x all tn
        const int bid = blockIdx.x;
        const int lin = (bid & 7) * (gridDim.x >> 3) + (bid >> 3);
        tm = lin >> ntnShift; tn = lin & ((1 << ntnShift) - 1);
    } else if (MODE == 4) {    // tm set per pass inside the loop
        tn = blockIdx.x >> 3;
    } else {
        tn = blockIdx.x; tm = blockIdx.y;
    }

    __shared__ __align__(16) char As[NWROW * 64 * 128];
    __shared__ __align__(16) char Bs[128 * 128];

    const int tid = threadIdx.x, lane = tid & 63, wave = tid >> 6;
    const int wm = wave % NWROW, wn = wave / NWROW;
    const int quad = lane >> 4, l15 = lane & 15;
    const int p = l15 & 7;                 // swizzle parity of fragment rows
    const int r8 = lane >> 3, c8 = lane & 7;

    const char* Ab = (const char*)((DUAL && bz) ? A1 : A0) + (size_t)bz * sA * 2;
    const char* Bb = (const char*)((DUAL && bz) ? B1 : B0) + (size_t)bz * sB * 2;
    const float* bias = (DUAL && bz) ? bias1 : bias0;

    const size_t ldab = (size_t)lda * 2, ldbb = (size_t)ldb * 2;
    const char* gB = Bb + (size_t)(tn * 128 + wave * 8 + r8) * ldbb + (size_t)((c8 ^ r8) * 16);
    char* lA = As + wave * 1024;
    char* lB = Bs + wave * 1024;
    constexpr int BCALLS = 8 / NWROW;
    char* Cb = (char*)((DUAL && bz) ? C1 : C0) + (size_t)bz * sC * (OUT_F32 ? 4 : 2);

    for (int pass = 0; pass < PASSES; ++pass) {
        if (MODE == 4) tm = pass == 0 ? 15 - (blockIdx.x & 7) : (blockIdx.x & 7);

        int Keff = K;
        if (CKLIM) { int kl = (tm + 1) * 128; Keff = kl < K ? kl : K; }

        const char* gA = Ab + (size_t)(tm * (NWROW * 64) + wave * 8 + r8) * ldab + (size_t)((c8 ^ r8) * 16);

        floatx4 acc[4][4] = {};

        for (int k0 = 0; k0 < Keff; k0 += 64) {
            const size_t kb = (size_t)k0 * 2;
            #pragma unroll
            for (int c = 0; c < 4; ++c)
                gl2lds(gA + (size_t)(c * NWROW * 16) * ldab + kb, lA + c * NTHR * 16);
            #pragma unroll
            for (int c = 0; c < BCALLS; ++c)
                gl2lds(gB + (size_t)(c * NWROW * 16) * ldbb + kb, lB + c * NTHR * 16);
            __syncthreads();

            #pragma unroll
            for (int kk = 0; kk < 2; kk++) {
                short8 af[4], bfr[4];
                #pragma unroll
                for (int i = 0; i < 4; i++)
                    af[i] = *(const short8*)(As + (wm * 64 + i * 16 + l15) * 128 + (((kk * 4 + quad) ^ p) << 4));
                #pragma unroll
                for (int j = 0; j < 4; j++)
                    bfr[j] = *(const short8*)(Bs + (wn * 64 + j * 16 + l15) * 128 + (((kk * 4 + quad) ^ p) << 4));
                #pragma unroll
                for (int i = 0; i < 4; i++)
                    #pragma unroll
                    for (int j = 0; j < 4; j++)
                        acc[i][j] = __builtin_amdgcn_mfma_f32_16x16x32_bf16(af[i], bfr[j], acc[i][j], 0, 0, 0);
            }
            __syncthreads();
        }

        // Epilogue: C/D layout col = lane&15, row = quad*4 + reg  [verified]
        if constexpr (EPI == 1) {
            // exp + causal mask + rowsum atomics (replaces softmax kernel)
            float* rs = (float*)C1 + (size_t)bz * T;
            #pragma unroll
            for (int i = 0; i < 4; i++) {
                #pragma unroll
                for (int r = 0; r < 4; r++) {
                    const int m = tm * (NWROW * 64) + wm * 64 + i * 16 + quad * 4 + r;
                    float rsum = 0.f;
                    #pragma unroll
                    for (int j = 0; j < 4; j++) {
                        const int n = tn * 128 + wn * 64 + j * 16 + l15;
                        float e = 0.f;
                        if (n <= m) e = __expf(acc[i][j][r] * scale);
                        rsum += e;
                        ((unsigned short*)Cb)[(size_t)m * ldc + n] = f2bf(e);
                    }
                    rsum += __shfl_xor(rsum, 1);
                    rsum += __shfl_xor(rsum, 2);
                    rsum += __shfl_xor(rsum, 4);
                    rsum += __shfl_xor(rsum, 8);
                    if (l15 == 0) atomicAdd(&rs[m], rsum);
                }
            }
        } else {
            float inv[4][4];
            if constexpr (EPI == 2) {
                const float* rsp = bias0 + (size_t)bz * T;
                #pragma unroll
                for (int i = 0; i < 4; i++)
                    #pragma unroll
                    for (int r = 0; r < 4; r++) {
                        const int m = tm * (NWROW * 64) + wm * 64 + i * 16 + quad * 4 + r;
                        inv[i][r] = 1.0f / rsp[m];
                    }
            }
            #pragma unroll
            for (int i = 0; i < 4; i++) {
                #pragma unroll
                for (int j = 0; j < 4; j++) {
                    const int n = tn * 128 + wn * 64 + j * 16 + l15;
                    #pragma unroll
                    for (int r = 0; r < 4; r++) {
                        const int m = tm * (NWROW * 64) + wm * 64 + i * 16 + quad * 4 + r;
                        float val = acc[i][j][r] * scale;
                        if (BIAS_MODE == 1) val += bias[n];
                        if (BIAS_MODE == 2) val += bias[m];
                        if (EPI == 2) val *= inv[i][r];
                        if (OUT_F32) ((float*)Cb)[(size_t)m * ldc + n] = val;
                        else         ((unsigned short*)Cb)[(size_t)m * ldc + n] = f2bf(val);
                    }
                }
            }
        }
    }
}

// Fused steps 1+2: one launch, block-range decode. Blocks 0..1023 = qp/kp
// projections; blocks 1024..1535 = vpT. bid%8 (XCD) preserved for both.
__global__ __launch_bounds__(256, 4) void fused12(
    const unsigned short* __restrict__ qb, const unsigned short* __restrict__ kb,
    const unsigned short* __restrict__ vb,
    const unsigned short* __restrict__ wqb, const unsigned short* __restrict__ wkb,
    const unsigned short* __restrict__ wvb,
    const float* __restrict__ wq_b, const float* __restrict__ wk_b,
    const float* __restrict__ wv_b,
    unsigned short* __restrict__ qp, unsigned short* __restrict__ kp,
    unsigned short* __restrict__ vpT)
{
    const int bid = blockIdx.x;
    const unsigned short *A, *B; const float* bias; unsigned short* C;
    int tm, tn, ldc, biasN;   // biasN: 1 -> bias[n], 0 -> bias[m]
    if (bid < 1024) {
        const int z = bid >> 9, l0 = bid & 511;
        const int lin = (l0 & 7) * 64 + (l0 >> 3);
        tm = lin >> 3; tn = lin & 7;
        A = z ? kb : qb; B = z ? wkb : wqb; bias = z ? wk_b : wq_b; C = z ? kp : qp;
        ldc = NE; biasN = 1;
    } else {
        const int t = bid - 1024, z = t >> 7, l0 = t & 127;
        const int lin = (l0 & 7) * 16 + (l0 >> 3);
        tm = lin >> 4; tn = lin & 15;
        A = wvb; B = vb + (size_t)z * T * NE; bias = wv_b; C = vpT + (size_t)z * NE * T;
        ldc = T; biasN = 0;
    }

    __shared__ __align__(16) char As[128 * 128];
    __shared__ __align__(16) char Bs[128 * 128];

    const int tid = threadIdx.x, lane = tid & 63, wave = tid >> 6;
    const int wm = wave & 1, wn = wave >> 1;
    const int quad = lane >> 4, l15 = lane & 15;
    const int p = l15 & 7;
    const int r8 = lane >> 3, c8 = lane & 7;

    const size_t ldab = (size_t)NE * 2;
    const char* gA = (const char*)A + (size_t)(tm * 128 + wave * 8 + r8) * ldab + (size_t)((c8 ^ r8) * 16);
    const char* gB = (const char*)B + (size_t)(tn * 128 + wave * 8 + r8) * ldab + (size_t)((c8 ^ r8) * 16);
    char* lA = As + wave * 1024;
    char* lB = Bs + wave * 1024;

    floatx4 acc[4][4] = {};

    for (int k0 = 0; k0 < NE; k0 += 64) {
        const size_t kb2 = (size_t)k0 * 2;
        #pragma unroll
        for (int c = 0; c < 4; ++c)
            gl2lds(gA + (size_t)(c * 32) * ldab + kb2, lA + c * 4096);
        #pragma unroll
        for (int c = 0; c < 4; ++c)
            gl2lds(gB + (size_t)(c * 32) * ldab + kb2, lB + c * 4096);
        __syncthreads();

        #pragma unroll
        for (int kk = 0; kk < 2; kk++) {
            short8 af[4], bfr[4];
            #pragma unroll
            for (int i = 0; i < 4; i++)
                af[i] = *(const short8*)(As + (wm * 64 + i * 16 + l15) * 128 + (((kk * 4 + quad) ^ p) << 4));
            #pragma unroll
            for (int j = 0; j < 4; j++)
                bfr[j] = *(const short8*)(Bs + (wn * 64 + j * 16 + l15) * 128 + (((kk * 4 + quad) ^ p) << 4));
            #pragma unroll
            for (int i = 0; i < 4; i++)
                #pragma unroll
                for (int j = 0; j < 4; j++)
                    acc[i][j] = __builtin_amdgcn_mfma_f32_16x16x32_bf16(af[i], bfr[j], acc[i][j], 0, 0, 0);
        }
        __syncthreads();
    }

    #pragma unroll
    for (int i = 0; i < 4; i++) {
        #pragma unroll
        for (int j = 0; j < 4; j++) {
            const int n = tn * 128 + wn * 64 + j * 16 + l15;
            #pragma unroll
            for (int r = 0; r < 4; r++) {
                const int m = tm * 128 + wm * 64 + i * 16 + quad * 4 + r;
                float val = acc[i][j][r] + (biasN ? bias[n] : bias[m]);
                C[(size_t)m * ldc + n] = f2bf(val);
            }
        }
    }
}

// Bulk f32->bf16: q,k,v then wq,wk,wv. One float4 per thread, PLAIN
// loads/stores (nt falsified in r11: downstream consumers refetched cold).
// Last 8 blocks zero the 32 KB rowsum buffer — replaces the hipMemsetAsync
// dispatch (+1 launch boundary) with 8 extra blocks here.
__global__ __launch_bounds__(256) void cvt_all(
    const float* __restrict__ q, const float* __restrict__ k, const float* __restrict__ v,
    const float* __restrict__ wq, const float* __restrict__ wk, const float* __restrict__ wv,
    unsigned short* __restrict__ qb, unsigned short* __restrict__ kb, unsigned short* __restrict__ vb,
    unsigned short* __restrict__ wqb, unsigned short* __restrict__ wkb, unsigned short* __restrict__ wvb,
    float* __restrict__ rowsum)
{
    const int IN4 = NB * T * NE / 4;   // 2^21
    const int W4  = NE * NE / 4;       // 2^18
    const int NCONV = (3 * IN4 + 3 * W4) / 256;   // 27648, exact
    if (blockIdx.x >= NCONV) {
        const int z = (blockIdx.x - NCONV) * 256 + threadIdx.x;  // < 2048
        ((floatx4*)rowsum)[z] = floatx4{0.f, 0.f, 0.f, 0.f};
        return;
    }
    int i = blockIdx.x * 256 + threadIdx.x;
    const float* s; unsigned short* d; int j;
    if (i < 3 * IN4) {
        int sel = i >> 21; j = i & (IN4 - 1);
        s = sel == 0 ? q : sel == 1 ? k : v;
        d = sel == 0 ? qb : sel == 1 ? kb : vb;
    } else {
        int t2 = i - 3 * IN4; int sel = t2 >> 18; j = t2 & (W4 - 1);
        s = sel == 0 ? wq : sel == 1 ? wk : wv;
        d = sel == 0 ? wqb : sel == 1 ? wkb : wvb;
    }
    floatx4 f = ((const floatx4*)s)[j];
    ((shortx4*)d)[j] = cvt4(f);
}

extern "C" void kernel_launch(void* const* d_in, const int* in_sizes, int n_in,
                              void* d_out, int out_size, void* d_ws, size_t ws_size,
                              hipStream_t stream)
{
    const float* q    = (const float*)d_in[0];
    const float* k    = (const float*)d_in[1];
    const float* v    = (const float*)d_in[2];
    const float* wq_w = (const float*)d_in[3];
    const float* wq_b = (const float*)d_in[4];
    const float* wk_w = (const float*)d_in[5];
    const float* wk_b = (const float*)d_in[6];
    const float* wv_w = (const float*)d_in[7];
    const float* wv_b = (const float*)d_in[8];

    const size_t INEL = (size_t)NB * T * NE;

    unsigned short* qp = (unsigned short*)d_out;        // qp/kp scratch in d_out
    unsigned short* kp = qp + INEL;

    unsigned short* vpT = (unsigned short*)d_ws;        // [0, 16.8) MB
    unsigned short* S   = vpT + (size_t)NB * NE * T;    // [16.8, 50.3) MB
    unsigned short* qb  = S;                            // staging overlaps S in
    unsigned short* kb  = qb + INEL;                    // space, disjoint in
    unsigned short* vb  = kb + INEL;                    // time; vb/w* extend
    unsigned short* wqb = vb + INEL;                    // past S to 73.4 MB
    unsigned short* wkb = wqb + (size_t)NE * NE;
    unsigned short* wvb = wkb + (size_t)NE * NE;
    // rowsum: 32 KB at 74 MB — past the staging end (73.4 MB), written by
    // nothing but cvt_all's zero-blocks and step3's atomics.
    float* rowsum = (float*)((char*)d_ws + 74ull * 1024 * 1024);

    dim3 blk(256);

    // 0) all f32 -> bf16, + 8 tail blocks zero rowsum (no memset dispatch)
    const int NCVT = (3 * (int)(INEL / 4) + 3 * NE * NE / 4) / 256 + 8;
    cvt_all<<<dim3(NCVT), blk, 0, stream>>>(q, k, v, wq_w, wk_w, wv_w,
                                            qb, kb, vb, wqb, wkb, wvb, rowsum);

    // 1+2) qp/kp projections AND vpT in ONE launch (1536 blocks, range-decoded)
    fused12<<<dim3(1536), blk, 0, stream>>>(
        qb, kb, vb, wqb, wkb, wvb, wq_b, wk_b, wv_b, qp, kp, vpT);

    // 3) S[b] = exp(qp_b @ kp_b^T / 32) with causal mask + rowsum atomics —
    //    136 tri tiles (128x128), xcd-grouped. Softmax denominators inline.
    gemm_bf16<2, 0, false, false, false, 2, 1><<<dim3(136, 1, NB), blk, 0, stream>>>(
        qp, nullptr, kp, nullptr, nullptr, nullptr, S, rowsum,
        NE, NE, NE, T, (size_t)T * NE, (size_t)T * NE, (size_t)T * T, 0.03125f, 0);

    // 5) O[b] = D^-1 (P_b @ vpT_b^T) — MODE 4 complementary pairs: 64 blk/z,
    //    every block 34 K-iters (bit-equal per CU; kills the K-imbalance tail)
    gemm_bf16<2, 0, true, true, false, 4, 2><<<dim3(64, 1, NB), blk, 0, stream>>>(
        S, nullptr, vpT, nullptr, rowsum, nullptr, d_out, nullptr,
        T, T, T, NE, (size_t)T * T, (size_t)NE * T, (size_t)T * NE, 1.0f, 0);
}